// Round 1
// baseline (1108.726 us; speedup 1.0000x reference)
//
#include <hip/hip_runtime.h>
#include <math.h>

// ---------------------------------------------------------------------------
// AttnEncoder: 2-layer GAT on two graphs + softmax gating head.
// Strategy:
//  - CSR-by-dst build per graph (counting sort, int atomics only)
//  - GEMM h = x@W with W in LDS, fused per-node scalars s=h.a_src, d=h.a_dst
//  - Aggregation: one wave per node, 2-pass softmax over incoming edges,
//    vectorized float2 gather of h[src] rows, no float atomics
//  - Prediction head: one wave per node
// ---------------------------------------------------------------------------

#define LRELU(v) ((v) > 0.f ? (v) : 0.2f * (v))

// ---- CSR build kernels -----------------------------------------------------

__global__ void k_init_counts(int* off_o, int* off_s, int n) {
    int i = blockIdx.x * 256 + threadIdx.x;
    if (i < n) { off_o[i] = 1; off_s[i] = 1; }   // self loop per node
}

__global__ void k_count(const int* __restrict__ dst_o, const int* __restrict__ dst_s,
                        int* off_o, int* off_s, int e) {
    int i = blockIdx.x * 256 + threadIdx.x;
    if (i < e) {
        atomicAdd(&off_o[dst_o[i]], 1);
        atomicAdd(&off_s[dst_s[i]], 1);
    }
}

// single-block exclusive scan over n counts; off[n] = total
__global__ __launch_bounds__(1024) void k_scan(int* off, int n) {
    __shared__ int sums[1024];
    int t = threadIdx.x;
    int per = (n + 1023) >> 10;
    int b = t * per;
    int e = min(b + per, n);
    int s = 0;
    for (int i = b; i < e; i++) s += off[i];
    sums[t] = s;
    __syncthreads();
    for (int d = 1; d < 1024; d <<= 1) {
        int v = (t >= d) ? sums[t - d] : 0;
        __syncthreads();
        sums[t] += v;
        __syncthreads();
    }
    int excl = (t == 0) ? 0 : sums[t - 1];
    if (t == 1023) off[n] = sums[1023];
    for (int i = b; i < e; i++) {
        int c = off[i];
        off[i] = excl;
        excl += c;
    }
}

__global__ void k_selfloop(const int* __restrict__ off_o, const int* __restrict__ off_s,
                           int* idx_o, int* idx_s, int* cur_o, int* cur_s, int n) {
    int i = blockIdx.x * 256 + threadIdx.x;
    if (i < n) {
        int p = off_o[i]; idx_o[p] = i; cur_o[i] = p + 1;
        int q = off_s[i]; idx_s[q] = i; cur_s[i] = q + 1;
    }
}

__global__ void k_fill(const int* __restrict__ src_o, const int* __restrict__ dst_o,
                       const int* __restrict__ src_s, const int* __restrict__ dst_s,
                       int* cur_o, int* cur_s, int* idx_o, int* idx_s, int e) {
    int i = blockIdx.x * 256 + threadIdx.x;
    if (i < e) {
        int p = atomicAdd(&cur_o[dst_o[i]], 1);
        idx_o[p] = src_o[i];
        int q = atomicAdd(&cur_s[dst_s[i]], 1);
        idx_s[q] = src_s[i];
    }
}

// ---- GEMM: H = X @ W, plus per-node scalars S = H.a_src, D = H.a_dst ------
// Block = 256 (4 waves). W (128x128 fp32, 64KB) staged in LDS.
// Each block handles 16 rows/iter; each wave handles 4 rows (register blocked
// so W is read from LDS once per 4 rows). Lane owns output cols (2l, 2l+1).

__global__ __launch_bounds__(256) void k_gemm(
    const float* __restrict__ X, const float* __restrict__ W,
    const float* __restrict__ a_src, const float* __restrict__ a_dst,
    float* __restrict__ H, float* __restrict__ Svec, float* __restrict__ Dvec,
    int n)
{
    __shared__ float Wl[128 * 128];
    {
        const float4* W4 = (const float4*)W;
        float4* L4 = (float4*)Wl;
        for (int i = threadIdx.x; i < (128 * 128 / 4); i += 256) L4[i] = W4[i];
    }
    __shared__ float Xs[16][128];

    int wave = threadIdx.x >> 6;
    int lane = threadIdx.x & 63;
    float as0 = a_src[2 * lane], as1 = a_src[2 * lane + 1];
    float ad0 = a_dst[2 * lane], ad1 = a_dst[2 * lane + 1];
    __syncthreads();

    int stride = gridDim.x * 16;
    for (int base = blockIdx.x * 16; base < n; base += stride) {
        __syncthreads();
        // stage 16 rows (512 float4s) cooperatively
        for (int i = threadIdx.x; i < 512; i += 256) {
            int r = i >> 5;
            int c = i & 31;
            int row = base + r;
            float4 v = (row < n) ? ((const float4*)(X + (size_t)row * 128))[c]
                                 : make_float4(0.f, 0.f, 0.f, 0.f);
            ((float4*)Xs[r])[c] = v;
        }
        __syncthreads();

        int r0 = wave * 4;
        float acc[4][2] = {{0.f,0.f},{0.f,0.f},{0.f,0.f},{0.f,0.f}};
        #pragma unroll 8
        for (int k = 0; k < 128; k++) {
            float2 w2 = *(const float2*)&Wl[k * 128 + 2 * lane];
            float x0 = Xs[r0 + 0][k];
            float x1 = Xs[r0 + 1][k];
            float x2 = Xs[r0 + 2][k];
            float x3 = Xs[r0 + 3][k];
            acc[0][0] += x0 * w2.x; acc[0][1] += x0 * w2.y;
            acc[1][0] += x1 * w2.x; acc[1][1] += x1 * w2.y;
            acc[2][0] += x2 * w2.x; acc[2][1] += x2 * w2.y;
            acc[3][0] += x3 * w2.x; acc[3][1] += x3 * w2.y;
        }
        for (int rr = 0; rr < 4; rr++) {
            int row = base + r0 + rr;
            if (row >= n) break;
            float2 o; o.x = acc[rr][0]; o.y = acc[rr][1];
            *(float2*)&H[(size_t)row * 128 + 2 * lane] = o;
            float s = acc[rr][0] * as0 + acc[rr][1] * as1;
            float d = acc[rr][0] * ad0 + acc[rr][1] * ad1;
            for (int m = 32; m; m >>= 1) {
                s += __shfl_xor(s, m);
                d += __shfl_xor(d, m);
            }
            if (lane == 0) { Svec[row] = s; Dvec[row] = d; }
        }
    }
}

// ---- GAT aggregation: one wave per node, 2-pass softmax over CSR edges ----

__global__ __launch_bounds__(256) void k_agg(
    const float* __restrict__ H, const float* __restrict__ Svec,
    const float* __restrict__ Dvec,
    const int* __restrict__ off, const int* __restrict__ idx,
    const float* __restrict__ bias, float* __restrict__ out,
    int n, int do_relu)
{
    int wave = threadIdx.x >> 6;
    int lane = threadIdx.x & 63;
    int node = blockIdx.x * 4 + wave;
    if (node >= n) return;

    int beg = off[node];
    int end = off[node + 1];
    float dn = Dvec[node];

    // pass 1: max logit (lanes parallel over edges)
    float m = -INFINITY;
    for (int j = beg + lane; j < end; j += 64) {
        float v = Svec[idx[j]] + dn;
        v = LRELU(v);
        m = fmaxf(m, v);
    }
    for (int o = 32; o; o >>= 1) m = fmaxf(m, __shfl_xor(m, o));

    // pass 2: weighted sum (chunks of 64 edges; w,src broadcast via shuffle)
    float acc0 = 0.f, acc1 = 0.f, denom = 0.f;
    for (int base = beg; base < end; base += 64) {
        int cnt = min(64, end - base);
        float w = 0.f;
        int s = 0;
        if (lane < cnt) {
            s = idx[base + lane];
            float v = Svec[s] + dn;
            v = LRELU(v);
            w = __expf(v - m);
        }
        denom += w;
        for (int kk = 0; kk < cnt; kk++) {
            float wk = __shfl(w, kk);
            int sk = __shfl(s, kk);
            float2 hv = *(const float2*)&H[(size_t)sk * 128 + 2 * lane];
            acc0 += wk * hv.x;
            acc1 += wk * hv.y;
        }
    }
    for (int o = 32; o; o >>= 1) denom += __shfl_xor(denom, o);
    float inv = 1.f / (denom + 1e-16f);
    float2 bv = *(const float2*)&bias[2 * lane];
    float o0 = acc0 * inv + bv.x;
    float o1 = acc1 * inv + bv.y;
    if (do_relu) { o0 = fmaxf(o0, 0.f); o1 = fmaxf(o1, 0.f); }
    float2 ov; ov.x = o0; ov.y = o1;
    *(float2*)&out[(size_t)node * 128 + 2 * lane] = ov;
}

// ---- prediction head -------------------------------------------------------

__global__ __launch_bounds__(256) void k_pred(
    const float* __restrict__ x2o, const float* __restrict__ x2s,
    const float* __restrict__ deg,
    const float* __restrict__ Wp, const float* __restrict__ bp,
    float* __restrict__ out, int n)
{
    int wave = threadIdx.x >> 6;
    int lane = threadIdx.x & 63;
    int node = blockIdx.x * 4 + wave;
    if (node >= n) return;

    float acc0 = 0.f, acc1 = 0.f;
    for (int i = lane; i < 288; i += 64) {
        float v;
        if (i < 128)      v = x2o[(size_t)node * 128 + i];
        else if (i < 256) v = x2s[(size_t)node * 128 + (i - 128)];
        else              v = deg[(size_t)node * 32 + (i - 256)];
        acc0 += v * Wp[i * 2];
        acc1 += v * Wp[i * 2 + 1];
    }
    for (int o = 32; o; o >>= 1) {
        acc0 += __shfl_xor(acc0, o);
        acc1 += __shfl_xor(acc1, o);
    }
    float z0 = acc0 + bp[0];
    float z1 = acc1 + bp[1];
    float mz = fmaxf(z0, z1);
    float e0 = __expf(z0 - mz);
    float e1 = __expf(z1 - mz);
    float a0 = e0 / (e0 + e1);
    float a1 = 1.f - a0;
    float2 vo = *(const float2*)&x2o[(size_t)node * 128 + 2 * lane];
    float2 vs = *(const float2*)&x2s[(size_t)node * 128 + 2 * lane];
    float2 r;
    r.x = a0 * vo.x + a1 * vs.x;
    r.y = a0 * vo.y + a1 * vs.y;
    *(float2*)&out[(size_t)node * 128 + 2 * lane] = r;
}

// ---- launch ----------------------------------------------------------------

extern "C" void kernel_launch(void* const* d_in, const int* in_sizes, int n_in,
                              void* d_out, int out_size, void* d_ws, size_t ws_size,
                              hipStream_t stream) {
    const float* x_o    = (const float*)d_in[0];
    const float* degree = (const float*)d_in[1];
    const int*   ei_o   = (const int*)d_in[2];
    const int*   ei_s   = (const int*)d_in[3];
    const float* W_o1 = (const float*)d_in[4];
    const float* asr_o1 = (const float*)d_in[5];
    const float* ads_o1 = (const float*)d_in[6];
    const float* b_o1 = (const float*)d_in[7];
    const float* W_o2 = (const float*)d_in[8];
    const float* asr_o2 = (const float*)d_in[9];
    const float* ads_o2 = (const float*)d_in[10];
    const float* b_o2 = (const float*)d_in[11];
    const float* W_s1 = (const float*)d_in[12];
    const float* asr_s1 = (const float*)d_in[13];
    const float* ads_s1 = (const float*)d_in[14];
    const float* b_s1 = (const float*)d_in[15];
    const float* W_s2 = (const float*)d_in[16];
    const float* asr_s2 = (const float*)d_in[17];
    const float* ads_s2 = (const float*)d_in[18];
    const float* b_s2 = (const float*)d_in[19];
    const float* W_pred = (const float*)d_in[20];
    const float* b_pred = (const float*)d_in[21];
    float* out = (float*)d_out;

    const int N = in_sizes[0] / 128;
    const int E = in_sizes[2] / 2;
    const int M = E + N;   // edges incl. self loops per graph

    // workspace layout (256B aligned slabs)
    char* ws = (char*)d_ws;
    size_t o = 0;
    auto alloc = [&](size_t bytes) -> char* {
        char* p = ws + o;
        o += (bytes + 255) & ~(size_t)255;
        return p;
    };
    int* off_o = (int*)alloc((size_t)(N + 1) * 4);
    int* off_s = (int*)alloc((size_t)(N + 1) * 4);
    int* cur_o = (int*)alloc((size_t)N * 4);
    int* cur_s = (int*)alloc((size_t)N * 4);
    int* idx_o = (int*)alloc((size_t)M * 4);
    int* idx_s = (int*)alloc((size_t)M * 4);
    float* Svec = (float*)alloc((size_t)N * 4);
    float* Dvec = (float*)alloc((size_t)N * 4);
    float* h  = (float*)alloc((size_t)N * 128 * 4);
    float* B1 = (float*)alloc((size_t)N * 128 * 4);  // x1_o then x2_o
    float* B2 = (float*)alloc((size_t)N * 128 * 4);  // x1_s then x2_s
    (void)ws_size;

    dim3 blk(256);
    int gN = (N + 255) / 256;
    int gE = (E + 255) / 256;
    int gGemm = (N + 15) / 16;
    int gNode = (N + 3) / 4;

    // CSR build for both graphs
    k_init_counts<<<gN, blk, 0, stream>>>(off_o, off_s, N);
    k_count<<<gE, blk, 0, stream>>>(ei_o + E, ei_s + E, off_o, off_s, E);
    k_scan<<<1, 1024, 0, stream>>>(off_o, N);
    k_scan<<<1, 1024, 0, stream>>>(off_s, N);
    k_selfloop<<<gN, blk, 0, stream>>>(off_o, off_s, idx_o, idx_s, cur_o, cur_s, N);
    k_fill<<<gE, blk, 0, stream>>>(ei_o, ei_o + E, ei_s, ei_s + E,
                                   cur_o, cur_s, idx_o, idx_s, E);

    // branch o
    k_gemm<<<gGemm, blk, 0, stream>>>(x_o, W_o1, asr_o1, ads_o1, h, Svec, Dvec, N);
    k_agg<<<gNode, blk, 0, stream>>>(h, Svec, Dvec, off_o, idx_o, b_o1, B1, N, 1);
    k_gemm<<<gGemm, blk, 0, stream>>>(B1, W_o2, asr_o2, ads_o2, h, Svec, Dvec, N);
    k_agg<<<gNode, blk, 0, stream>>>(h, Svec, Dvec, off_o, idx_o, b_o2, B1, N, 0);

    // branch s
    k_gemm<<<gGemm, blk, 0, stream>>>(x_o, W_s1, asr_s1, ads_s1, h, Svec, Dvec, N);
    k_agg<<<gNode, blk, 0, stream>>>(h, Svec, Dvec, off_s, idx_s, b_s1, B2, N, 1);
    k_gemm<<<gGemm, blk, 0, stream>>>(B2, W_s2, asr_s2, ads_s2, h, Svec, Dvec, N);
    k_agg<<<gNode, blk, 0, stream>>>(h, Svec, Dvec, off_s, idx_s, b_s2, B2, N, 0);

    // head
    k_pred<<<gNode, blk, 0, stream>>>(B1, B2, degree, W_pred, b_pred, out, N);
}

// Round 2
// 722.639 us; speedup vs baseline: 1.5343x; 1.5343x over previous
//
#include <hip/hip_runtime.h>
#include <math.h>

// ---------------------------------------------------------------------------
// AttnEncoder: 2-layer GAT on two graphs + softmax gating head.
//  - Bucketed CSR build: bin edges by dst>>7 with line-local scatter, then
//    per-bucket LDS counting sort -> off/idx written coalesced, block-owned.
//  - GEMM h = x@W with W in LDS, fused per-node scalars s=h.a_src, d=h.a_dst
//  - Aggregation: one wave per node, 2-pass softmax; float4 gathers, two
//    edge rows per iteration (lane halves), no float atomics.
// ---------------------------------------------------------------------------

#define LRELU(v) ((v) > 0.f ? (v) : 0.2f * (v))

#define BSHIFT 7
#define BSIZE  128          // nodes per bucket
#define MAXB   512          // max buckets (requires N <= 65536)
#define CHUNK  4096         // edges per binning block
#define EPT    16           // edges per thread in binning
#define MAXE   4352         // per-bucket edge capacity in sort staging

// ---- CSR build -------------------------------------------------------------

__global__ void k_zero(int* a, int* b, int n) {
    int i = blockIdx.x * 512 + threadIdx.x;
    if (i < n) { a[i] = 0; b[i] = 0; }
}

__global__ __launch_bounds__(256) void k_bin_count(
    const int* __restrict__ dst_o, const int* __restrict__ dst_s,
    int* bcnt_o, int* bcnt_s, int E)
{
    __shared__ int cnt[2 * MAXB];
    for (int i = threadIdx.x; i < 2 * MAXB; i += 256) cnt[i] = 0;
    __syncthreads();
    int base = blockIdx.x * CHUNK;
    for (int i = threadIdx.x; i < CHUNK; i += 256) {
        int e = base + i;
        if (e < E) {
            atomicAdd(&cnt[dst_o[e] >> BSHIFT], 1);
            atomicAdd(&cnt[MAXB + (dst_s[e] >> BSHIFT)], 1);
        }
    }
    __syncthreads();
    for (int b = threadIdx.x; b < MAXB; b += 256) {
        int c0 = cnt[b];        if (c0) atomicAdd(&bcnt_o[b], c0);
        int c1 = cnt[MAXB + b]; if (c1) atomicAdd(&bcnt_s[b], c1);
    }
}

__global__ __launch_bounds__(512) void k_bscan(
    const int* __restrict__ bcnt_o, const int* __restrict__ bcnt_s,
    int* bbase_o, int* bbase_s, int* bcur_o, int* bcur_s, int nbuck)
{
    __shared__ int a[512], b[512];
    int t = threadIdx.x;
    int ca = (t < nbuck) ? bcnt_o[t] : 0;
    int cb = (t < nbuck) ? bcnt_s[t] : 0;
    a[t] = ca; b[t] = cb;
    __syncthreads();
    for (int d = 1; d < 512; d <<= 1) {
        int va = (t >= d) ? a[t - d] : 0;
        int vb = (t >= d) ? b[t - d] : 0;
        __syncthreads();
        a[t] += va; b[t] += vb;
        __syncthreads();
    }
    if (t < nbuck) {
        int eo = a[t] - ca, es = b[t] - cb;
        bbase_o[t] = eo; bcur_o[t] = eo;
        bbase_s[t] = es; bcur_s[t] = es;
    }
    if (t == nbuck - 1) { bbase_o[nbuck] = a[t]; bbase_s[nbuck] = b[t]; }
}

__global__ __launch_bounds__(256) void k_bin_scatter(
    const int* __restrict__ src_o, const int* __restrict__ dst_o,
    const int* __restrict__ src_s, const int* __restrict__ dst_s,
    int* bcur_o, int* bcur_s, int* ebin_o, int* ebin_s, int E)
{
    __shared__ int cnt[MAXB];
    __shared__ int gb[MAXB];
    int t = threadIdx.x;
    int base = blockIdx.x * CHUNK;

    for (int g = 0; g < 2; g++) {
        const int* srcp = g ? src_s : src_o;
        const int* dstp = g ? dst_s : dst_o;
        int* bcur = g ? bcur_s : bcur_o;
        int* ebin = g ? ebin_s : ebin_o;
        for (int i = t; i < MAXB; i += 256) cnt[i] = 0;
        __syncthreads();
        int pk[EPT], bk[EPT], rk[EPT];
        #pragma unroll
        for (int j = 0; j < EPT; j++) {
            int e = base + j * 256 + t;
            bk[j] = -1; pk[j] = 0; rk[j] = 0;
            if (e < E) {
                int d = dstp[e];
                int s = srcp[e];
                int bb = d >> BSHIFT;
                bk[j] = bb;
                pk[j] = ((d & (BSIZE - 1)) << 16) | s;
                rk[j] = atomicAdd(&cnt[bb], 1);
            }
        }
        __syncthreads();
        for (int i = t; i < MAXB; i += 256) {
            int c = cnt[i];
            gb[i] = c ? atomicAdd(&bcur[i], c) : 0;
        }
        __syncthreads();
        #pragma unroll
        for (int j = 0; j < EPT; j++) {
            if (bk[j] >= 0) ebin[gb[bk[j]] + rk[j]] = pk[j];
        }
        __syncthreads();
    }
}

// one block per bucket: LDS counting sort to CSR order, coalesced dump
__global__ __launch_bounds__(256) void k_sort(
    const int* __restrict__ ebin_o, const int* __restrict__ bbase_o,
    int* __restrict__ off_o, int* __restrict__ idx_o,
    const int* __restrict__ ebin_s, const int* __restrict__ bbase_s,
    int* __restrict__ off_s, int* __restrict__ idx_s,
    int N, int nbuck, int E)
{
    const int* ebin  = blockIdx.y ? ebin_s  : ebin_o;
    const int* bbase = blockIdx.y ? bbase_s : bbase_o;
    int* off = blockIdx.y ? off_s : off_o;
    int* idx = blockIdx.y ? idx_s : idx_o;

    __shared__ int pack[MAXE];
    __shared__ int sorted[MAXE + BSIZE];
    __shared__ int cnt[BSIZE + 1];
    __shared__ int s2[BSIZE + 1];
    __shared__ int noff[BSIZE + 1];

    int b = blockIdx.x;
    int t = threadIdx.x;
    int node0 = b << BSHIFT;
    int nloc = min(BSIZE, N - node0);
    int ebeg = bbase[b];
    int ne = min(bbase[b + 1] - ebeg, MAXE);

    for (int i = t; i < ne; i += 256) pack[i] = ebin[ebeg + i];
    if (t < BSIZE + 1) cnt[t] = (t < nloc) ? 1 : 0;   // self loop reserved
    __syncthreads();
    for (int i = t; i < ne; i += 256) atomicAdd(&cnt[pack[i] >> 16], 1);
    __syncthreads();
    if (t < BSIZE + 1) s2[t] = cnt[t];
    __syncthreads();
    for (int d = 1; d <= BSIZE; d <<= 1) {
        int v = (t < BSIZE + 1 && t >= d) ? s2[t - d] : 0;
        __syncthreads();
        if (t < BSIZE + 1) s2[t] += v;
        __syncthreads();
    }
    if (t < BSIZE + 1) noff[t] = s2[t] - cnt[t];      // exclusive
    __syncthreads();
    if (t < nloc) {
        cnt[t] = noff[t] + 1;                          // cursor past self loop
        sorted[noff[t]] = node0 + t;                   // self loop entry
        off[node0 + t] = ebeg + node0 + noff[t];
    }
    __syncthreads();
    for (int i = t; i < ne; i += 256) {
        int p = atomicAdd(&cnt[pack[i] >> 16], 1);
        sorted[p] = pack[i] & 0xffff;
    }
    __syncthreads();
    int tot = ne + nloc;
    for (int i = t; i < tot; i += 256) idx[ebeg + node0 + i] = sorted[i];
    if (b == nbuck - 1 && t == 0) off[N] = E + N;
}

// ---- GEMM: H = X @ W, plus per-node scalars S = H.a_src, D = H.a_dst ------

__global__ __launch_bounds__(256) void k_gemm(
    const float* __restrict__ X, const float* __restrict__ W,
    const float* __restrict__ a_src, const float* __restrict__ a_dst,
    float* __restrict__ H, float* __restrict__ Svec, float* __restrict__ Dvec,
    int n)
{
    __shared__ float Wl[128 * 128];
    {
        const float4* W4 = (const float4*)W;
        float4* L4 = (float4*)Wl;
        for (int i = threadIdx.x; i < (128 * 128 / 4); i += 256) L4[i] = W4[i];
    }
    __shared__ float Xs[16][128];

    int wave = threadIdx.x >> 6;
    int lane = threadIdx.x & 63;
    float as0 = a_src[2 * lane], as1 = a_src[2 * lane + 1];
    float ad0 = a_dst[2 * lane], ad1 = a_dst[2 * lane + 1];
    __syncthreads();

    int stride = gridDim.x * 16;
    for (int base = blockIdx.x * 16; base < n; base += stride) {
        __syncthreads();
        for (int i = threadIdx.x; i < 512; i += 256) {
            int r = i >> 5;
            int c = i & 31;
            int row = base + r;
            float4 v = (row < n) ? ((const float4*)(X + (size_t)row * 128))[c]
                                 : make_float4(0.f, 0.f, 0.f, 0.f);
            ((float4*)Xs[r])[c] = v;
        }
        __syncthreads();

        int r0 = wave * 4;
        float acc[4][2] = {{0.f,0.f},{0.f,0.f},{0.f,0.f},{0.f,0.f}};
        #pragma unroll 8
        for (int k = 0; k < 128; k++) {
            float2 w2 = *(const float2*)&Wl[k * 128 + 2 * lane];
            float x0 = Xs[r0 + 0][k];
            float x1 = Xs[r0 + 1][k];
            float x2 = Xs[r0 + 2][k];
            float x3 = Xs[r0 + 3][k];
            acc[0][0] += x0 * w2.x; acc[0][1] += x0 * w2.y;
            acc[1][0] += x1 * w2.x; acc[1][1] += x1 * w2.y;
            acc[2][0] += x2 * w2.x; acc[2][1] += x2 * w2.y;
            acc[3][0] += x3 * w2.x; acc[3][1] += x3 * w2.y;
        }
        for (int rr = 0; rr < 4; rr++) {
            int row = base + r0 + rr;
            if (row >= n) break;
            float2 o; o.x = acc[rr][0]; o.y = acc[rr][1];
            *(float2*)&H[(size_t)row * 128 + 2 * lane] = o;
            float s = acc[rr][0] * as0 + acc[rr][1] * as1;
            float d = acc[rr][0] * ad0 + acc[rr][1] * ad1;
            for (int m = 32; m; m >>= 1) {
                s += __shfl_xor(s, m);
                d += __shfl_xor(d, m);
            }
            if (lane == 0) { Svec[row] = s; Dvec[row] = d; }
        }
    }
}

// ---- GAT aggregation: one wave per node, 2-pass softmax over CSR edges ----

__global__ __launch_bounds__(256) void k_agg(
    const float* __restrict__ H, const float* __restrict__ Svec,
    const float* __restrict__ Dvec,
    const int* __restrict__ off, const int* __restrict__ idx,
    const float* __restrict__ bias, float* __restrict__ out,
    int n, int do_relu)
{
    int wave = threadIdx.x >> 6;
    int lane = threadIdx.x & 63;
    int node = blockIdx.x * 4 + wave;
    if (node >= n) return;

    int beg = off[node];
    int end = off[node + 1];
    float dn = Dvec[node];

    // pass 1: max logit
    float m = -INFINITY;
    for (int j = beg + lane; j < end; j += 64) {
        float v = Svec[idx[j]] + dn;
        m = fmaxf(m, LRELU(v));
    }
    #pragma unroll
    for (int o = 32; o; o >>= 1) m = fmaxf(m, __shfl_xor(m, o));

    // pass 2: weighted sum — two edge rows per iter, float4 per lane
    int half = lane >> 5;           // 0: even edges, 1: odd edges
    int col4 = (lane & 31) << 2;    // this lane's 4 channels
    float a0 = 0.f, a1 = 0.f, a2 = 0.f, a3 = 0.f, denom = 0.f;
    for (int base = beg; base < end; base += 64) {
        int cnt = min(64, end - base);
        float w = 0.f;
        int s = 0;
        if (lane < cnt) {
            s = idx[base + lane];
            float v = Svec[s] + dn;
            w = __expf(LRELU(v) - m);
        }
        denom += w;
        for (int kk = 0; kk < cnt; kk += 2) {
            int k0 = kk + half;               // k0==cnt on odd tail -> w==0
            float wk = __shfl(w, k0);
            int   sk = __shfl(s, k0);
            float4 hv = *(const float4*)&H[(size_t)sk * 128 + col4];
            a0 += wk * hv.x; a1 += wk * hv.y; a2 += wk * hv.z; a3 += wk * hv.w;
        }
    }
    // combine halves (same channels in lane L and L^32)
    a0 += __shfl_xor(a0, 32);
    a1 += __shfl_xor(a1, 32);
    a2 += __shfl_xor(a2, 32);
    a3 += __shfl_xor(a3, 32);
    #pragma unroll
    for (int o = 32; o; o >>= 1) denom += __shfl_xor(denom, o);

    if (half == 0) {
        float inv = 1.f / (denom + 1e-16f);
        float4 bv = *(const float4*)&bias[col4];
        float4 ov;
        ov.x = a0 * inv + bv.x;
        ov.y = a1 * inv + bv.y;
        ov.z = a2 * inv + bv.z;
        ov.w = a3 * inv + bv.w;
        if (do_relu) {
            ov.x = fmaxf(ov.x, 0.f); ov.y = fmaxf(ov.y, 0.f);
            ov.z = fmaxf(ov.z, 0.f); ov.w = fmaxf(ov.w, 0.f);
        }
        *(float4*)&out[(size_t)node * 128 + col4] = ov;
    }
}

// ---- prediction head -------------------------------------------------------

__global__ __launch_bounds__(256) void k_pred(
    const float* __restrict__ x2o, const float* __restrict__ x2s,
    const float* __restrict__ deg,
    const float* __restrict__ Wp, const float* __restrict__ bp,
    float* __restrict__ out, int n)
{
    int wave = threadIdx.x >> 6;
    int lane = threadIdx.x & 63;
    int node = blockIdx.x * 4 + wave;
    if (node >= n) return;

    float acc0 = 0.f, acc1 = 0.f;
    for (int i = lane; i < 288; i += 64) {
        float v;
        if (i < 128)      v = x2o[(size_t)node * 128 + i];
        else if (i < 256) v = x2s[(size_t)node * 128 + (i - 128)];
        else              v = deg[(size_t)node * 32 + (i - 256)];
        acc0 += v * Wp[i * 2];
        acc1 += v * Wp[i * 2 + 1];
    }
    for (int o = 32; o; o >>= 1) {
        acc0 += __shfl_xor(acc0, o);
        acc1 += __shfl_xor(acc1, o);
    }
    float z0 = acc0 + bp[0];
    float z1 = acc1 + bp[1];
    float mz = fmaxf(z0, z1);
    float e0 = __expf(z0 - mz);
    float e1 = __expf(z1 - mz);
    float a0 = e0 / (e0 + e1);
    float a1 = 1.f - a0;
    float2 vo = *(const float2*)&x2o[(size_t)node * 128 + 2 * lane];
    float2 vs = *(const float2*)&x2s[(size_t)node * 128 + 2 * lane];
    float2 r;
    r.x = a0 * vo.x + a1 * vs.x;
    r.y = a0 * vo.y + a1 * vs.y;
    *(float2*)&out[(size_t)node * 128 + 2 * lane] = r;
}

// ---- launch ----------------------------------------------------------------

extern "C" void kernel_launch(void* const* d_in, const int* in_sizes, int n_in,
                              void* d_out, int out_size, void* d_ws, size_t ws_size,
                              hipStream_t stream) {
    const float* x_o    = (const float*)d_in[0];
    const float* degree = (const float*)d_in[1];
    const int*   ei_o   = (const int*)d_in[2];
    const int*   ei_s   = (const int*)d_in[3];
    const float* W_o1 = (const float*)d_in[4];
    const float* asr_o1 = (const float*)d_in[5];
    const float* ads_o1 = (const float*)d_in[6];
    const float* b_o1 = (const float*)d_in[7];
    const float* W_o2 = (const float*)d_in[8];
    const float* asr_o2 = (const float*)d_in[9];
    const float* ads_o2 = (const float*)d_in[10];
    const float* b_o2 = (const float*)d_in[11];
    const float* W_s1 = (const float*)d_in[12];
    const float* asr_s1 = (const float*)d_in[13];
    const float* ads_s1 = (const float*)d_in[14];
    const float* b_s1 = (const float*)d_in[15];
    const float* W_s2 = (const float*)d_in[16];
    const float* asr_s2 = (const float*)d_in[17];
    const float* ads_s2 = (const float*)d_in[18];
    const float* b_s2 = (const float*)d_in[19];
    const float* W_pred = (const float*)d_in[20];
    const float* b_pred = (const float*)d_in[21];
    float* out = (float*)d_out;

    const int N = in_sizes[0] / 128;
    const int E = in_sizes[2] / 2;
    const int M = E + N;
    const int NBUCK = (N + BSIZE - 1) >> BSHIFT;   // requires N <= 65536

    char* ws = (char*)d_ws;
    size_t o = 0;
    auto alloc = [&](size_t bytes) -> char* {
        char* p = ws + o;
        o += (bytes + 255) & ~(size_t)255;
        return p;
    };
    int* bcnt_o  = (int*)alloc((size_t)(NBUCK + 1) * 4);
    int* bcnt_s  = (int*)alloc((size_t)(NBUCK + 1) * 4);
    int* bbase_o = (int*)alloc((size_t)(NBUCK + 1) * 4);
    int* bbase_s = (int*)alloc((size_t)(NBUCK + 1) * 4);
    int* bcur_o  = (int*)alloc((size_t)NBUCK * 4);
    int* bcur_s  = (int*)alloc((size_t)NBUCK * 4);
    int* off_o   = (int*)alloc((size_t)(N + 1) * 4);
    int* off_s   = (int*)alloc((size_t)(N + 1) * 4);
    int* idx_o   = (int*)alloc((size_t)M * 4);
    int* idx_s   = (int*)alloc((size_t)M * 4);
    float* Svec  = (float*)alloc((size_t)N * 4);
    float* Dvec  = (float*)alloc((size_t)N * 4);
    float* h  = (float*)alloc((size_t)N * 128 * 4);
    float* B1 = (float*)alloc((size_t)N * 128 * 4);
    float* B2 = (float*)alloc((size_t)N * 128 * 4);
    (void)ws_size;

    // ebin overlays h (dead after k_sort; h first written by k_gemm after)
    int* ebin_o = (int*)h;
    int* ebin_s = (int*)h + E;

    dim3 blk(256);
    int gBin  = (E + CHUNK - 1) / CHUNK;
    int gGemm = (N + 15) / 16;
    int gNode = (N + 3) / 4;

    // CSR build (both graphs together)
    k_zero<<<1, 512, 0, stream>>>(bcnt_o, bcnt_s, NBUCK + 1);
    k_bin_count<<<gBin, blk, 0, stream>>>(ei_o + E, ei_s + E, bcnt_o, bcnt_s, E);
    k_bscan<<<1, 512, 0, stream>>>(bcnt_o, bcnt_s, bbase_o, bbase_s, bcur_o, bcur_s, NBUCK);
    k_bin_scatter<<<gBin, blk, 0, stream>>>(ei_o, ei_o + E, ei_s, ei_s + E,
                                            bcur_o, bcur_s, ebin_o, ebin_s, E);
    dim3 gSort(NBUCK, 2);
    k_sort<<<gSort, blk, 0, stream>>>(ebin_o, bbase_o, off_o, idx_o,
                                      ebin_s, bbase_s, off_s, idx_s, N, NBUCK, E);

    // branch o
    k_gemm<<<gGemm, blk, 0, stream>>>(x_o, W_o1, asr_o1, ads_o1, h, Svec, Dvec, N);
    k_agg<<<gNode, blk, 0, stream>>>(h, Svec, Dvec, off_o, idx_o, b_o1, B1, N, 1);
    k_gemm<<<gGemm, blk, 0, stream>>>(B1, W_o2, asr_o2, ads_o2, h, Svec, Dvec, N);
    k_agg<<<gNode, blk, 0, stream>>>(h, Svec, Dvec, off_o, idx_o, b_o2, B1, N, 0);

    // branch s
    k_gemm<<<gGemm, blk, 0, stream>>>(x_o, W_s1, asr_s1, ads_s1, h, Svec, Dvec, N);
    k_agg<<<gNode, blk, 0, stream>>>(h, Svec, Dvec, off_s, idx_s, b_s1, B2, N, 1);
    k_gemm<<<gGemm, blk, 0, stream>>>(B2, W_s2, asr_s2, ads_s2, h, Svec, Dvec, N);
    k_agg<<<gNode, blk, 0, stream>>>(h, Svec, Dvec, off_s, idx_s, b_s2, B2, N, 0);

    // head
    k_pred<<<gNode, blk, 0, stream>>>(B1, B2, degree, W_pred, b_pred, out, N);
}